// Round 3
// baseline (657.742 us; speedup 1.0000x reference)
//
#include <hip/hip_runtime.h>
#include <hip/hip_bf16.h>
#include <math.h>

using bf16 = __hip_bfloat16;
typedef __attribute__((ext_vector_type(8))) short bfx8;   // 8 x bf16 MFMA frag
typedef __attribute__((ext_vector_type(4))) float fx4;    // MFMA accum

#define DI __device__ __forceinline__

#define B_  4
#define L_  2048
#define D_  1024
#define M_  256
#define N_  8192            /* B*L tokens */
#define H_  256
#define CCH 32              /* scan chunks per sequence */
#define TCH 64              /* chunk length; CCH*TCH == L_ */

DI float us2f(unsigned short u){ unsigned int i=((unsigned int)u)<<16; float f; __builtin_memcpy(&f,&i,4); return f; }
DI unsigned short f2bu(float f){ bf16 h=__float2bfloat16(f); unsigned short u; __builtin_memcpy(&u,&h,2); return u; }
DI float b2f(bf16 v){ return __bfloat162float(v); }
DI float siluf(float x){ return x/(1.f+expf(-x)); }
DI float geluf(float x){ return 0.5f*x*(1.f+erff(x*0.70710678118654752f)); }

DI void gload_lds16(const bf16* g, bf16* l){
  __builtin_amdgcn_global_load_lds((const __attribute__((address_space(1))) void*)g,
                                   (__attribute__((address_space(3))) void*)l, 16, 0, 0);
}

// ---------------- f32 -> bf16 hi/lo split (weights) ----------------
__global__ __launch_bounds__(256) void k_split(const float* __restrict__ w, bf16* __restrict__ hi,
                                               bf16* __restrict__ lo, int n4)
{
  int i = blockIdx.x*256 + threadIdx.x;
  const int stride = gridDim.x*256;
  for (; i<n4; i+=stride){
    const float4 f = ((const float4*)w)[i];
    ushort4 h, l;
    h.x=f2bu(f.x); l.x=f2bu(f.x-us2f(h.x));
    h.y=f2bu(f.y); l.y=f2bu(f.y-us2f(h.y));
    h.z=f2bu(f.z); l.z=f2bu(f.z-us2f(h.z));
    h.w=f2bu(f.w); l.w=f2bu(f.w-us2f(h.w));
    ((ushort4*)hi)[i]=h; ((ushort4*)lo)[i]=l;
  }
}

__global__ __launch_bounds__(256) void k_cast(const float* __restrict__ w, bf16* __restrict__ o, int n4)
{
  int i = blockIdx.x*256 + threadIdx.x;
  const int stride = gridDim.x*256;
  for (; i<n4; i+=stride){
    const float4 f = ((const float4*)w)[i];
    ushort4 h;
    h.x=f2bu(f.x); h.y=f2bu(f.y); h.z=f2bu(f.z); h.w=f2bu(f.w);
    ((ushort4*)o)[i]=h;
  }
}

// ---------------- RMS norm (block = 1 token, 256 thr, 4 elems/thr) ----------------
template<bool BF_OUT2>
__global__ __launch_bounds__(256) void k_rms(const float* __restrict__ inp, const float* __restrict__ w,
                                             float* __restrict__ outf, bf16* __restrict__ outbf)
{
  const int n = blockIdx.x, t = threadIdx.x;
  const float4 f = *((const float4*)inp + (size_t)n*(D_/4) + t);
  float s = f.x*f.x+f.y*f.y+f.z*f.z+f.w*f.w;
  #pragma unroll
  for (int off=32; off; off>>=1) s += __shfl_xor(s, off, 64);
  __shared__ float red[4];
  if ((t&63)==0) red[t>>6]=s;
  __syncthreads();
  const float inv = 1.f/sqrtf((red[0]+red[1]+red[2]+red[3])*(1.f/(float)D_)+1e-6f);
  const float4 wv = *((const float4*)w + t);
  float4 of;
  of.x = wv.x*f.x*inv; of.y = wv.y*f.y*inv; of.z = wv.z*f.z*inv; of.w = wv.w*f.w*inv;
  *((float4*)outf + (size_t)n*(D_/4) + t) = of;
  if constexpr (BF_OUT2){
    ushort4 ub; ub.x=f2bu(of.x); ub.y=f2bu(of.y); ub.z=f2bu(of.z); ub.w=f2bu(of.w);
    *((ushort4*)outbf + (size_t)n*(D_/4) + t) = ub;
  }
}

// ---------------- causal depthwise conv K=5 (block = 1 token); out split hi/lo ----------------
__global__ __launch_bounds__(256) void k_conv(const float* __restrict__ h0, const float* __restrict__ dww,
                                              const float* __restrict__ dwb,
                                              bf16* __restrict__ yhi, bf16* __restrict__ ylo)
{
  const int n = blockIdx.x, t = threadIdx.x;
  const int l = n & (L_-1);
  const int d0 = t*4;
  float a0=dwb[d0+0], a1=dwb[d0+1], a2=dwb[d0+2], a3=dwb[d0+3];
  #pragma unroll
  for (int k=0;k<5;k++){
    if (l-4+k < 0) continue;         // uniform across block
    const float4 h4 = *(const float4*)&h0[(size_t)(n+k-4)*D_ + d0];
    a0 += h4.x*dww[(d0+0)*5+k];
    a1 += h4.y*dww[(d0+1)*5+k];
    a2 += h4.z*dww[(d0+2)*5+k];
    a3 += h4.w*dww[(d0+3)*5+k];
  }
  ushort4 hi, lo;
  hi.x=f2bu(a0); lo.x=f2bu(a0-us2f(hi.x));
  hi.y=f2bu(a1); lo.y=f2bu(a1-us2f(hi.y));
  hi.z=f2bu(a2); lo.z=f2bu(a2-us2f(hi.z));
  hi.w=f2bu(a3); lo.w=f2bu(a3-us2f(hi.w));
  *((ushort4*)yhi + (size_t)n*(D_/4) + t) = hi;
  *((ushort4*)ylo + (size_t)n*(D_/4) + t) = lo;
}

// ---------------- chunked linear-recurrence scan ----------------
__global__ __launch_bounds__(256) void k_scan1(const float* __restrict__ v, float* __restrict__ wv,
                                               float* __restrict__ carry, const float* __restrict__ td)
{
  const int bc = blockIdx.x, m = threadIdx.x;
  const int b = bc>>5, c = bc&(CCH-1);
  const float decay = 0.9f/(1.f+expf(-td[m])) + 0.1f;
  const float* vp = v  + ((size_t)b*L_ + c*TCH)*M_ + m;
  float*       wp = wv + ((size_t)b*L_ + c*TCH)*M_ + m;
  float a = 0.f;
  #pragma unroll 4
  for (int i=0;i<TCH;i++){ a = a*decay + vp[(size_t)i*M_]; wp[(size_t)i*M_] = a; }
  carry[(size_t)bc*M_ + m] = a;
}

__global__ void k_scan2(float* __restrict__ carry, const float* __restrict__ td)
{
  const int b = blockIdx.x, m = threadIdx.x;
  const float decay = 0.9f/(1.f+expf(-td[m])) + 0.1f;
  const float dT = powf(decay, (float)TCH);
  float cin = 0.f;
  for (int c=0;c<CCH;c++){
    const size_t idx = ((size_t)(b*CCH+c))*M_ + m;
    const float e = carry[idx];
    carry[idx] = cin;
    cin = e + dT*cin;
  }
}

__global__ __launch_bounds__(256) void k_scan3(const float* __restrict__ wv, const float* __restrict__ carry,
                                               const float* __restrict__ mem, const float* __restrict__ td,
                                               const float* __restrict__ tf,
                                               bf16* __restrict__ wvhi, bf16* __restrict__ wvlo,
                                               float* __restrict__ nextmem)
{
  const int bc = blockIdx.x, m = threadIdx.x;
  const int b = bc>>5, c = bc&(CCH-1);
  const float decay = 0.9f/(1.f+expf(-td[m])) + 0.1f;
  const float cin = carry[(size_t)bc*M_ + m];
  const float memc = mem[b*M_+m] / (1.f+expf(-tf[m]));
  const float* wp = wv + ((size_t)b*L_ + c*TCH)*M_ + m;
  float p = 1.f;
  for (int i=0;i<TCH;i++){
    p *= decay;
    const float val = wp[(size_t)i*M_] + p*cin + memc;
    const int l = c*TCH+i;
    const size_t n = (size_t)b*L_ + l;
    const unsigned short h = f2bu(val);
    wvhi[n*M_ + m] = *(const bf16*)&h;
    const unsigned short lo = f2bu(val - us2f(h));
    wvlo[n*M_ + m] = *(const bf16*)&lo;
    if (l == L_-1) nextmem[b*M_+m] = val;
  }
}

// ---------------- router: f32 logits, top-2 softmax -> dense gates ----------------
__global__ __launch_bounds__(256) void k_router(const float* __restrict__ h2, const float* __restrict__ rw,
                                                const float* __restrict__ rb, float* __restrict__ gates)
{
  const int wv_ = threadIdx.x>>6, lane = threadIdx.x&63;
  const size_t n = (size_t)blockIdx.x*4 + wv_;
  const float4* row = (const float4*)(h2 + n*D_);
  const float4* rwv = (const float4*)rw;
  float p0=0,p1=0,p2=0,p3=0;
  #pragma unroll
  for (int j=0;j<4;j++){
    const float4 xv = row[j*64 + lane];
    const int cb = j*64 + lane;
    const float4 w0 = rwv[cb], w1 = rwv[256+cb], w2 = rwv[512+cb], w3 = rwv[768+cb];
    p0 += xv.x*w0.x+xv.y*w0.y+xv.z*w0.z+xv.w*w0.w;
    p1 += xv.x*w1.x+xv.y*w1.y+xv.z*w1.z+xv.w*w1.w;
    p2 += xv.x*w2.x+xv.y*w2.y+xv.z*w2.z+xv.w*w2.w;
    p3 += xv.x*w3.x+xv.y*w3.y+xv.z*w3.z+xv.w*w3.w;
  }
  #pragma unroll
  for (int off=32; off; off>>=1){
    p0 += __shfl_xor(p0, off, 64); p1 += __shfl_xor(p1, off, 64);
    p2 += __shfl_xor(p2, off, 64); p3 += __shfl_xor(p3, off, 64);
  }
  if (lane==0){
    float lg[4] = {p0+rb[0], p1+rb[1], p2+rb[2], p3+rb[3]};
    int i1=0; float m1=lg[0];
    #pragma unroll
    for (int e=1;e<4;e++) if (lg[e]>m1){ m1=lg[e]; i1=e; }
    int i2=-1; float m2=-1e30f;
    #pragma unroll
    for (int e=0;e<4;e++) if (e!=i1 && lg[e]>m2){ m2=lg[e]; i2=e; }
    const float ex = expf(m2-m1);
    const float w1 = 1.f/(1.f+ex), w2 = ex/(1.f+ex);
    float4 g; g.x=0; g.y=0; g.z=0; g.w=0;
    ((float*)&g)[i1]=w1; ((float*)&g)[i2]=w2;
    *(float4*)&gates[n*4] = g;
  }
}

// ---------------- MFMA GEMM: C[n,o] = act( sum_k A[n,k]*W[o,k] + b[o] ) ----------------
// SPLIT modes run 3 passes (Ah*Wh + Al*Wh + Ah*Wl) for ~2^-17 relative error.
enum GMode { MODE_PW=0, MODE_VAL, MODE_GATE, MODE_EXP0, MODE_EXP, MODE_EXPL, MODE_OUTW, MODE_DOWN, MODE_UP };

template<int MODE>
__global__ __launch_bounds__(256)
void k_gemm(const bf16* __restrict__ Ah, const bf16* __restrict__ Al, const int lda,
            const bf16* __restrict__ A2h, const bf16* __restrict__ A2l,   // gate: wv segment (ld 256)
            const bf16* __restrict__ Wh, const bf16* __restrict__ Wl, const int K,
            const float* __restrict__ bias,
            float* __restrict__ Cf, const int ldc,
            bf16* __restrict__ Cb1, bf16* __restrict__ Cb2, const int ldcb,
            const float* __restrict__ resf, const int ldres,
            const float* __restrict__ gates,
            const float* __restrict__ xin, const float* __restrict__ rs)
{
  constexpr bool SPLIT = (MODE==MODE_PW || MODE==MODE_VAL || MODE==MODE_GATE);
  constexpr bool DUAL  = (MODE==MODE_GATE);
  __shared__ __align__(16) bf16 smem[SPLIT ? 16384 : 8192];
  bf16* Ash = smem;
  bf16* Wsh = smem + 4096;
  bf16* Asl = smem + (SPLIT ? 8192 : 0);
  bf16* Wsl = smem + (SPLIT ? 12288 : 0);

  const int t = threadIdx.x, wave = t>>6, lane = t&63;
  const int brow = blockIdx.y*128, bcol = blockIdx.x*128;
  const int wm = wave>>1, wn = wave&1;
  fx4 acc[4][4] = {};
  const int sr = t>>2, sc = (t&3)*8;

  const size_t rg = (size_t)(brow+sr);
  const bf16* gAh0 = Ah + rg*lda + sc;
  const bf16* gAh1 = gAh0 + (size_t)64*lda;
  const bf16* gAl0 = SPLIT ? Al + rg*lda + sc : nullptr;
  const bf16* gAl1 = SPLIT ? gAl0 + (size_t)64*lda : nullptr;
  const bf16* gWh0 = Wh + (size_t)(bcol+sr)*K + sc;
  const bf16* gWh1 = gWh0 + (size_t)64*K;
  const bf16* gWl0 = SPLIT ? Wl + (size_t)(bcol+sr)*K + sc : nullptr;
  const bf16* gWl1 = SPLIT ? gWl0 + (size_t)64*K : nullptr;
  const bf16* g2h0 = DUAL ? A2h + rg*M_ + sc : nullptr;
  const bf16* g2h1 = DUAL ? g2h0 + (size_t)64*M_ : nullptr;
  const bf16* g2l0 = DUAL ? A2l + rg*M_ + sc : nullptr;
  const bf16* g2l1 = DUAL ? g2l0 + (size_t)64*M_ : nullptr;

  bf16* dA  = Ash + wave*512;
  bf16* dW  = Wsh + wave*512;
  bf16* dAl = Asl + wave*512;
  bf16* dWl = Wsl + wave*512;

  for (int kk=0; kk<K; kk+=32){
    __syncthreads();
    if (!DUAL || kk < 1024){
      gload_lds16(gAh0 + kk, dA);
      gload_lds16(gAh1 + kk, dA + 2048);
      if constexpr (SPLIT){
        gload_lds16(gAl0 + kk, dAl);
        gload_lds16(gAl1 + kk, dAl + 2048);
      }
    } else {
      const int k2 = kk - 1024;
      gload_lds16(g2h0 + k2, dA);
      gload_lds16(g2h1 + k2, dA + 2048);
      gload_lds16(g2l0 + k2, dAl);
      gload_lds16(g2l1 + k2, dAl + 2048);
    }
    gload_lds16(gWh0 + kk, dW);
    gload_lds16(gWh1 + kk, dW + 2048);
    if constexpr (SPLIT){
      gload_lds16(gWl0 + kk, dWl);
      gload_lds16(gWl1 + kk, dWl + 2048);
    }
    __syncthreads();

    const int aoff = (wm*64 + (lane&15))*32 + (lane>>4)*8;
    const int boff = (wn*64 + (lane&15))*32 + (lane>>4)*8;
    bfx8 ah[4], al[4], wh[4], wl[4];
    #pragma unroll
    for (int i=0;i<4;i++){
      ah[i] = *(const bfx8*)&Ash[aoff + i*512];
      wh[i] = *(const bfx8*)&Wsh[boff + i*512];
      if constexpr (SPLIT){
        al[i] = *(const bfx8*)&Asl[aoff + i*512];
        wl[i] = *(const bfx8*)&Wsl[boff + i*512];
      }
    }
    #pragma unroll
    for (int i=0;i<4;i++){
      #pragma unroll
      for (int j=0;j<4;j++){
        acc[i][j] = __builtin_amdgcn_mfma_f32_16x16x32_bf16(ah[i], wh[j], acc[i][j], 0,0,0);
        if constexpr (SPLIT){
          acc[i][j] = __builtin_amdgcn_mfma_f32_16x16x32_bf16(al[i], wh[j], acc[i][j], 0,0,0);
          acc[i][j] = __builtin_amdgcn_mfma_f32_16x16x32_bf16(ah[i], wl[j], acc[i][j], 0,0,0);
        }
      }
    }
  }

  // epilogue: C/D layout col=lane&15, row=(lane>>4)*4+reg
  const int r0 = brow + wm*64 + (lane>>4)*4;
  const int c0 = bcol + wn*64 + (lane&15);
  float gv[4][4];
  if constexpr (MODE==MODE_EXP0 || MODE==MODE_EXP || MODE==MODE_EXPL){
    #pragma unroll
    for (int i=0;i<4;i++)
      #pragma unroll
      for (int r=0;r<4;r++) gv[i][r] = gates[(size_t)(r0+i*16+r)*4];
  }
  #pragma unroll
  for (int j=0;j<4;j++){
    const int col = c0 + j*16;
    const float bc = bias[col];
    #pragma unroll
    for (int i=0;i<4;i++){
      #pragma unroll
      for (int r=0;r<4;r++){
        const size_t rr = (size_t)(r0 + i*16 + r);
        float v = acc[i][j][r] + bc;
        if constexpr (MODE==MODE_PW){
          v = siluf(v);
          const unsigned short h = f2bu(v);
          Cb1[rr*ldcb+col] = *(const bf16*)&h;
          const unsigned short lo = f2bu(v - us2f(h));
          Cb2[rr*ldcb+col] = *(const bf16*)&lo;
        } else if constexpr (MODE==MODE_VAL){
          Cf[rr*ldc+col] = v;
        } else if constexpr (MODE==MODE_GATE){
          v += b2f(Ah[rr*(size_t)lda+col]) + b2f(Al[rr*(size_t)lda+col]);  // + h1 residual
          Cf[rr*ldc+col] = v;
          Cb1[rr*ldcb+col] = __float2bfloat16(v);
        } else if constexpr (MODE==MODE_EXP0 || MODE==MODE_EXP || MODE==MODE_EXPL){
          float val = gv[i][r]*siluf(v);
          const size_t ci = rr*ldc+col;
          if constexpr (MODE!=MODE_EXP0) val += Cf[ci];
          if constexpr (MODE!=MODE_EXPL) Cf[ci] = val;
          else                           Cb1[rr*ldcb+col] = __float2bfloat16(val);
        } else if constexpr (MODE==MODE_OUTW){
          Cf[rr*ldc+col] = v + resf[rr*ldres+col];
        } else if constexpr (MODE==MODE_DOWN){
          Cb1[rr*ldcb+col] = __float2bfloat16(geluf(v));
        } else if constexpr (MODE==MODE_UP){
          Cf[rr*ldc+col] = xin[rr*D_+col]*rs[0] + resf[rr*ldres+col] + v;
        }
      }
    }
  }
}

// ---------------- host launcher ----------------
// ws layout (MB offsets; peak ~118MB). Lifetimes verified acyclic:
//  [0,21): split/cast weights (persistent): pwh0 pwl2 valh4 vall4.5 gateh5 gatel7.5
//          expb10 outb18 downb20 upb20.5 ; gatesb @21
//  [22,54): h0 {rms1->conv} ; then vbuf[22,30) wvbuf[30,38) {val->scan3} ;
//           then h2bf[22,38) {gate->expl} ; then h3bf[22,38) {rms2->down}
//  [38,46): wvhi/wvlo {scan3->gate} ; then combbf[38,54) {expl->outw} ; then dbf[38,42) {down->up}
//  [46,46.2): carry {scan1->scan3}
//  [54,86): h1hi/h1lo {pw->gate} ; then tbuf f32 {outw->rms2}
//  [86,118): yhi/ylo {conv->pw} ; then h2 f32 {gate->outw} ; then h3 f32 {rms2->up}
//  comb f32 lives in d_out[0,32MB) {exp0->expl}; final UP overwrites; next_mem at +8388608 floats.
extern "C" void kernel_launch(void* const* d_in, const int* in_sizes, int n_in,
                              void* d_out, int out_size, void* d_ws, size_t ws_size,
                              hipStream_t stream)
{
  (void)in_sizes; (void)n_in; (void)out_size; (void)ws_size;
  const float* x       = (const float*)d_in[0];
  const float* mem     = (const float*)d_in[1];
  const float* norm_w  = (const float*)d_in[2];
  const float* dw_w    = (const float*)d_in[3];
  const float* dw_b    = (const float*)d_in[4];
  const float* pw_w    = (const float*)d_in[5];
  const float* pw_b    = (const float*)d_in[6];
  const float* val_w   = (const float*)d_in[7];
  const float* val_b   = (const float*)d_in[8];
  const float* td      = (const float*)d_in[9];
  const float* tf      = (const float*)d_in[10];
  const float* gate_w  = (const float*)d_in[11];
  const float* gate_b  = (const float*)d_in[12];
  const float* rw      = (const float*)d_in[13];
  const float* rb      = (const float*)d_in[14];
  const float* exp_w   = (const float*)d_in[15];
  const float* exp_b   = (const float*)d_in[16];
  const float* out_w   = (const float*)d_in[17];
  const float* out_b   = (const float*)d_in[18];
  const float* fnorm_w = (const float*)d_in[19];
  const float* down_w  = (const float*)d_in[20];
  const float* down_b  = (const float*)d_in[21];
  const float* up_w    = (const float*)d_in[22];
  const float* up_b    = (const float*)d_in[23];
  const float* rs      = (const float*)d_in[24];

  char* ws = (char*)d_ws;
  const size_t MB = 1048576;
  // weights
  bf16* pwh   = (bf16*)(ws + 0);
  bf16* pwl   = (bf16*)(ws + 2*MB);
  bf16* valh  = (bf16*)(ws + 4*MB);
  bf16* vall  = (bf16*)(ws + 4*MB + 524288);
  bf16* gateh = (bf16*)(ws + 5*MB);
  bf16* gatel = (bf16*)(ws + 7*MB + 524288);
  bf16* expb  = (bf16*)(ws + 10*MB);
  bf16* outb  = (bf16*)(ws + 18*MB);
  bf16* downb = (bf16*)(ws + 20*MB);
  bf16* upb   = (bf16*)(ws + 20*MB + 524288);
  float* gatesb = (float*)(ws + 21*MB);
  // activations (aliased by lifetime)
  float* h0    = (float*)(ws + 22*MB);
  float* vbuf  = (float*)(ws + 22*MB);
  float* wvbuf = (float*)(ws + 30*MB);
  bf16*  h2bf  = (bf16 *)(ws + 22*MB);
  bf16*  h3bf  = (bf16 *)(ws + 22*MB);
  bf16*  wvhi  = (bf16 *)(ws + 38*MB);
  bf16*  wvlo  = (bf16 *)(ws + 42*MB);
  bf16*  combbf= (bf16 *)(ws + 38*MB);
  bf16*  dbf   = (bf16 *)(ws + 38*MB);
  float* carry = (float*)(ws + 46*MB);
  bf16*  h1hi  = (bf16 *)(ws + 54*MB);
  bf16*  h1lo  = (bf16 *)(ws + 70*MB);
  float* tbuf  = (float*)(ws + 54*MB);
  bf16*  yhi   = (bf16 *)(ws + 86*MB);
  bf16*  ylo   = (bf16 *)(ws + 102*MB);
  float* h2    = (float*)(ws + 86*MB);
  float* h3    = (float*)(ws + 86*MB);

  float* out0 = (float*)d_out;                       // (B,L,D)
  float* nm   = (float*)d_out + (size_t)N_*D_;       // next_mem (B,M)
  float* comb = (float*)d_out;                       // scratch {exp0->expl}

  const dim3 blk(256);
  // weight conversion
  k_split<<<512, blk, 0, stream>>>(pw_w,   pwh,   pwl,   1048576/4);
  k_split<<<512, blk, 0, stream>>>(val_w,  valh,  vall,   262144/4);
  k_split<<<512, blk, 0, stream>>>(gate_w, gateh, gatel, 1310720/4);
  k_cast <<<512, blk, 0, stream>>>(exp_w,  expb,  4194304/4);
  k_cast <<<512, blk, 0, stream>>>(out_w,  outb,  1048576/4);
  k_cast <<<512, blk, 0, stream>>>(down_w, downb,  262144/4);
  k_cast <<<512, blk, 0, stream>>>(up_w,   upb,    262144/4);

  k_rms<false><<<N_, blk, 0, stream>>>(x, norm_w, h0, nullptr);
  k_conv<<<N_, blk, 0, stream>>>(h0, dw_w, dw_b, yhi, ylo);
  // h1 = silu(y @ pw_w^T + pw_b), split
  k_gemm<MODE_PW><<<dim3(8,64), blk, 0, stream>>>(yhi, ylo, D_, nullptr, nullptr, pwh, pwl, D_,
      pw_b, nullptr, 0, h1hi, h1lo, D_, nullptr, 0, nullptr, nullptr, nullptr);
  // v = h1 @ val_w^T + val_b
  k_gemm<MODE_VAL><<<dim3(2,64), blk, 0, stream>>>(h1hi, h1lo, D_, nullptr, nullptr, valh, vall, D_,
      val_b, vbuf, M_, nullptr, nullptr, 0, nullptr, 0, nullptr, nullptr, nullptr);
  k_scan1<<<B_*CCH, blk, 0, stream>>>(vbuf, wvbuf, carry, td);
  k_scan2<<<B_, blk, 0, stream>>>(carry, td);
  k_scan3<<<B_*CCH, blk, 0, stream>>>(wvbuf, carry, mem, td, tf, wvhi, wvlo, nm);
  // h2 = h1 + [h1|wv] @ gate_w^T + gate_b
  k_gemm<MODE_GATE><<<dim3(8,64), blk, 0, stream>>>(h1hi, h1lo, D_, wvhi, wvlo, gateh, gatel, 1280,
      gate_b, h2, D_, h2bf, nullptr, D_, nullptr, 0, nullptr, nullptr, nullptr);
  k_router<<<N_/4, blk, 0, stream>>>(h2, rw, rb, gatesb);
  // experts (dense, gate-weighted accumulate in comb=d_out)
  k_gemm<MODE_EXP0><<<dim3(8,64), blk, 0, stream>>>(h2bf, nullptr, D_, nullptr, nullptr, expb + (size_t)0*D_*D_, nullptr, D_,
      exp_b + 0*D_, comb, D_, nullptr, nullptr, 0, nullptr, 0, gatesb+0, nullptr, nullptr);
  k_gemm<MODE_EXP ><<<dim3(8,64), blk, 0, stream>>>(h2bf, nullptr, D_, nullptr, nullptr, expb + (size_t)1*D_*D_, nullptr, D_,
      exp_b + 1*D_, comb, D_, nullptr, nullptr, 0, nullptr, 0, gatesb+1, nullptr, nullptr);
  k_gemm<MODE_EXP ><<<dim3(8,64), blk, 0, stream>>>(h2bf, nullptr, D_, nullptr, nullptr, expb + (size_t)2*D_*D_, nullptr, D_,
      exp_b + 2*D_, comb, D_, nullptr, nullptr, 0, nullptr, 0, gatesb+2, nullptr, nullptr);
  k_gemm<MODE_EXPL><<<dim3(8,64), blk, 0, stream>>>(h2bf, nullptr, D_, nullptr, nullptr, expb + (size_t)3*D_*D_, nullptr, D_,
      exp_b + 3*D_, comb, D_, combbf, nullptr, D_, nullptr, 0, gatesb+3, nullptr, nullptr);
  // t = h2 + comb @ out_w^T + out_b
  k_gemm<MODE_OUTW><<<dim3(8,64), blk, 0, stream>>>(combbf, nullptr, D_, nullptr, nullptr, outb, nullptr, D_,
      out_b, tbuf, D_, nullptr, nullptr, 0, h2, D_, nullptr, nullptr, nullptr);
  // h3 = rms(t, fnorm_w)
  k_rms<true><<<N_, blk, 0, stream>>>(tbuf, fnorm_w, h3, h3bf);
  // d = gelu(h3 @ down_w^T + down_b)
  k_gemm<MODE_DOWN><<<dim3(2,64), blk, 0, stream>>>(h3bf, nullptr, D_, nullptr, nullptr, downb, nullptr, D_,
      down_b, nullptr, 0, dbf, nullptr, H_, nullptr, 0, nullptr, nullptr, nullptr);
  // out = x*rs + h3 + d @ up_w^T + up_b
  k_gemm<MODE_UP><<<dim3(8,64), blk, 0, stream>>>(dbf, nullptr, H_, nullptr, nullptr, upb, nullptr, H_,
      up_b, out0, D_, nullptr, nullptr, 0, h3, D_, nullptr, x, rs);
}